// Round 1
// baseline (1179.731 us; speedup 1.0000x reference)
//
#include <hip/hip_runtime.h>
#include <hip/hip_fp16.h>
#include <math.h>

#define NH    32
#define NKV   8
#define HD    128
#define DIM   4096
#define BATCH 32
#define KVLEN 4096
#define QKVN  6144   // (32 + 2*8) * 128

__host__ __device__ static inline int imin(int a, int b) { return a < b ? a : b; }

// ---------------------------------------------------------------------------
// K0: transpose x (32 x 4096) -> xT (4096 x 32) so GEMM activation reads are
// wave-uniform (scalar-loadable).
// ---------------------------------------------------------------------------
__global__ __launch_bounds__(256) void k_transpose_x(const float* __restrict__ x,
                                                     float* __restrict__ xT) {
    __shared__ float tile[32][65];
    int k0 = blockIdx.x * 64;
    int t = threadIdx.x;
#pragma unroll
    for (int i = 0; i < 8; ++i) {
        int idx = t + i * 256;          // 0..2047
        int bb = idx >> 6, kk = idx & 63;
        tile[bb][kk] = x[bb * DIM + k0 + kk];
    }
    __syncthreads();
#pragma unroll
    for (int i = 0; i < 8; ++i) {
        int idx = t + i * 256;
        int kk = idx >> 5, bb = idx & 31;
        xT[(k0 + kk) * 32 + bb] = tile[bb][kk];
    }
}

// ---------------------------------------------------------------------------
// K1/K4: skinny GEMM  C[b][j] = sum_k xT[k][b] * W[k][j],  M=32 fixed.
// Split-K across blocks; each chunk writes a partial slab; reduce kernel sums.
// One thread per output column j, 32 fp32 accumulators (one per batch row).
// xT reads are uniform across the wave -> s_load; W reads lane-contiguous.
// ---------------------------------------------------------------------------
__global__ __launch_bounds__(256) void k_gemm32_partial(
        const float* __restrict__ xT, const float* __restrict__ W,
        float* __restrict__ partial, int K, int N, int kchunk) {
    int jB = N >> 8;                 // blocks along j
    int jb = blockIdx.x % jB;
    int c  = blockIdx.x / jB;
    int j  = (jb << 8) + threadIdx.x;
    int k0 = c * kchunk;
    int k1 = imin(k0 + kchunk, K);
    float acc[32];
#pragma unroll
    for (int b = 0; b < 32; ++b) acc[b] = 0.f;
#pragma unroll 2
    for (int kk = k0; kk < k1; ++kk) {
        float w = W[(size_t)kk * N + j];
        const float* xr = xT + (kk << 5);
#pragma unroll
        for (int b = 0; b < 32; ++b) acc[b] = fmaf(xr[b], w, acc[b]);
    }
    float* P = partial + (size_t)c * 32 * N;
#pragma unroll
    for (int b = 0; b < 32; ++b) P[(size_t)b * N + j] = acc[b];
}

__global__ __launch_bounds__(256) void k_reduce_partial(
        const float* __restrict__ partial, float* __restrict__ C,
        int N, int nchunk) {
    int idx = blockIdx.x * 256 + threadIdx.x;   // over 32*N
    float s = 0.f;
    for (int c = 0; c < nchunk; ++c) s += partial[(size_t)c * 32 * N + idx];
    C[idx] = s;
}

// ---------------------------------------------------------------------------
// K2: RoPE (dense 128x128 rot matrix) + scatter k/v into caches at pos.
// grid = BATCH * 48 blocks of 128 threads.
//   slot 0..31  : q head -> qr (pre-scaled by 1/sqrt(HD))
//   slot 32..39 : k head -> rot -> cache_k[...,pos,:]
//   slot 40..47 : v head -> copy -> cache_v[...,pos,:]
// ---------------------------------------------------------------------------
__global__ __launch_bounds__(128) void k_rope_scatter(
        const float* __restrict__ xqkv, const float* __restrict__ rot,
        float* __restrict__ qr, float* __restrict__ cache_k,
        float* __restrict__ cache_v, const int* __restrict__ posp) {
    int blk = blockIdx.x;
    int b = blk / 48, slot = blk % 48;
    int e = threadIdx.x;
    int pos = *posp;
    if (slot < 32) {
        const float* src = xqkv + b * QKVN + slot * HD;
        float acc = 0.f;
        for (int d = 0; d < HD; ++d) acc = fmaf(src[d], rot[d * HD + e], acc);
        qr[b * (NH * HD) + slot * HD + e] = acc * 0.08838834764831845f; // 1/sqrt(128)
    } else if (slot < 40) {
        int kv = slot - 32;
        const float* src = xqkv + b * QKVN + NH * HD + kv * HD;
        float acc = 0.f;
        for (int d = 0; d < HD; ++d) acc = fmaf(src[d], rot[d * HD + e], acc);
        cache_k[(((size_t)(b * NKV + kv)) * KVLEN + pos) * HD + e] = acc;
    } else {
        int kv = slot - 40;
        cache_v[(((size_t)(b * NKV + kv)) * KVLEN + pos) * HD + e] =
            xqkv[b * QKVN + (NH + NKV) * HD + kv * HD + e];
    }
}

// ---------------------------------------------------------------------------
// K3: decode attention. One block (256 thr) per (b, kv). 4 query heads.
// Scores for 4 heads x KVLEN in LDS as half (32 KB). Two-pass softmax.
// 32 lanes cover one 128-float row as float4 -> each wave instr reads two
// contiguous 512B rows. shfl_xor reduce within 32-lane halves.
// ---------------------------------------------------------------------------
__global__ __launch_bounds__(256) void k_attn_decode(
        const float* __restrict__ qr, const float* __restrict__ cache_k,
        const float* __restrict__ cache_v, const int* __restrict__ posp,
        float* __restrict__ attnT) {
    __shared__ __half sc[4][KVLEN];      // 32 KB: scores then probs
    __shared__ float red[4][4];          // [wave][head]
    __shared__ float part[4][4][HD];     // [wave][head][dim] 8 KB
    __shared__ float hstat[8];           // max[4], sum[4]

    int L = *posp + 1;
    int bk = blockIdx.x;
    int b = bk >> 3, kv = bk & 7;
    int t = threadIdx.x;
    int wave = t >> 6, lane = t & 63;
    int hf = lane >> 5, l32 = lane & 31;
    int rowoff = wave * 2 + hf;          // 0..7; rows advance by 8

    // q fragments: head h, dims l32*4..+3 (pre-scaled in qr)
    float4 qv[4];
    {
        const float4* qb = (const float4*)(qr + b * (NH * HD) + kv * 4 * HD);
#pragma unroll
        for (int h = 0; h < 4; ++h) qv[h] = qb[h * 32 + l32];
    }

    const float4* Kb = (const float4*)(cache_k + ((size_t)(b * NKV + kv)) * KVLEN * HD);
    const float4* Vb = (const float4*)(cache_v + ((size_t)(b * NKV + kv)) * KVLEN * HD);

    // ---- score pass ----
    auto dot_write = [&](float4 k4, int s) {
        float p0 = k4.x * qv[0].x + k4.y * qv[0].y + k4.z * qv[0].z + k4.w * qv[0].w;
        float p1 = k4.x * qv[1].x + k4.y * qv[1].y + k4.z * qv[1].z + k4.w * qv[1].w;
        float p2 = k4.x * qv[2].x + k4.y * qv[2].y + k4.z * qv[2].z + k4.w * qv[2].w;
        float p3 = k4.x * qv[3].x + k4.y * qv[3].y + k4.z * qv[3].z + k4.w * qv[3].w;
#pragma unroll
        for (int m = 1; m <= 16; m <<= 1) {
            p0 += __shfl_xor(p0, m);
            p1 += __shfl_xor(p1, m);
            p2 += __shfl_xor(p2, m);
            p3 += __shfl_xor(p3, m);
        }
        if (l32 == 0) {
            sc[0][s] = __float2half(p0);
            sc[1][s] = __float2half(p1);
            sc[2][s] = __float2half(p2);
            sc[3][s] = __float2half(p3);
        }
    };
    int s = rowoff;
    for (; s + 24 < L; s += 32) {
        float4 a0 = Kb[(size_t)(s)      * 32 + l32];
        float4 a1 = Kb[(size_t)(s + 8)  * 32 + l32];
        float4 a2 = Kb[(size_t)(s + 16) * 32 + l32];
        float4 a3 = Kb[(size_t)(s + 24) * 32 + l32];
        dot_write(a0, s); dot_write(a1, s + 8);
        dot_write(a2, s + 16); dot_write(a3, s + 24);
    }
    for (; s < L; s += 8) dot_write(Kb[(size_t)s * 32 + l32], s);
    __syncthreads();

    // ---- max per head ----
    float mx[4] = {-3.0e38f, -3.0e38f, -3.0e38f, -3.0e38f};
    for (int i = t; i < L; i += 256) {
#pragma unroll
        for (int h = 0; h < 4; ++h) mx[h] = fmaxf(mx[h], __half2float(sc[h][i]));
    }
#pragma unroll
    for (int m = 1; m <= 32; m <<= 1) {
#pragma unroll
        for (int h = 0; h < 4; ++h) mx[h] = fmaxf(mx[h], __shfl_xor(mx[h], m));
    }
    if (lane == 0) {
#pragma unroll
        for (int h = 0; h < 4; ++h) red[wave][h] = mx[h];
    }
    __syncthreads();
    if (t < 4)
        hstat[t] = fmaxf(fmaxf(red[0][t], red[1][t]), fmaxf(red[2][t], red[3][t]));
    __syncthreads();

    // ---- exp + sum ----
    float m0 = hstat[0], m1 = hstat[1], m2 = hstat[2], m3 = hstat[3];
    float sm[4] = {0.f, 0.f, 0.f, 0.f};
    for (int i = t; i < L; i += 256) {
        float e0 = __expf(__half2float(sc[0][i]) - m0); sc[0][i] = __float2half(e0); sm[0] += e0;
        float e1 = __expf(__half2float(sc[1][i]) - m1); sc[1][i] = __float2half(e1); sm[1] += e1;
        float e2 = __expf(__half2float(sc[2][i]) - m2); sc[2][i] = __float2half(e2); sm[2] += e2;
        float e3 = __expf(__half2float(sc[3][i]) - m3); sc[3][i] = __float2half(e3); sm[3] += e3;
    }
#pragma unroll
    for (int m = 1; m <= 32; m <<= 1) {
#pragma unroll
        for (int h = 0; h < 4; ++h) sm[h] += __shfl_xor(sm[h], m);
    }
    if (lane == 0) {
#pragma unroll
        for (int h = 0; h < 4; ++h) red[wave][h] = sm[h];
    }
    __syncthreads();
    if (t < 4)
        hstat[4 + t] = red[0][t] + red[1][t] + red[2][t] + red[3][t];
    __syncthreads();

    // ---- V pass ----
    float4 acc[4];
#pragma unroll
    for (int h = 0; h < 4; ++h) acc[h] = make_float4(0.f, 0.f, 0.f, 0.f);
    auto vacc = [&](float4 v4, int s2) {
#pragma unroll
        for (int h = 0; h < 4; ++h) {
            float p = __half2float(sc[h][s2]);
            acc[h].x = fmaf(p, v4.x, acc[h].x);
            acc[h].y = fmaf(p, v4.y, acc[h].y);
            acc[h].z = fmaf(p, v4.z, acc[h].z);
            acc[h].w = fmaf(p, v4.w, acc[h].w);
        }
    };
    s = rowoff;
    for (; s + 24 < L; s += 32) {
        float4 a0 = Vb[(size_t)(s)      * 32 + l32];
        float4 a1 = Vb[(size_t)(s + 8)  * 32 + l32];
        float4 a2 = Vb[(size_t)(s + 16) * 32 + l32];
        float4 a3 = Vb[(size_t)(s + 24) * 32 + l32];
        vacc(a0, s); vacc(a1, s + 8); vacc(a2, s + 16); vacc(a3, s + 24);
    }
    for (; s < L; s += 8) vacc(Vb[(size_t)s * 32 + l32], s);

    // combine the two 32-lane halves (same dims, different rows)
#pragma unroll
    for (int h = 0; h < 4; ++h) {
        acc[h].x += __shfl_xor(acc[h].x, 32);
        acc[h].y += __shfl_xor(acc[h].y, 32);
        acc[h].z += __shfl_xor(acc[h].z, 32);
        acc[h].w += __shfl_xor(acc[h].w, 32);
    }
    if (hf == 0) {
#pragma unroll
        for (int h = 0; h < 4; ++h)
            ((float4*)part[wave][h])[l32] = acc[h];
    }
    __syncthreads();

    // ---- epilogue: sum wave partials, normalize, write attnT (4096 x 32) ----
    if (t < 128) {
        int h = t >> 5, d4 = t & 31;
        float4 r = ((float4*)part[0][h])[d4];
        float4 r1 = ((float4*)part[1][h])[d4];
        float4 r2 = ((float4*)part[2][h])[d4];
        float4 r3 = ((float4*)part[3][h])[d4];
        r.x += r1.x + r2.x + r3.x;
        r.y += r1.y + r2.y + r3.y;
        r.z += r1.z + r2.z + r3.z;
        r.w += r1.w + r2.w + r3.w;
        float inv = 1.f / hstat[4 + h];
        int dbase = (kv * 4 + h) * HD + d4 * 4;
        attnT[(size_t)(dbase + 0) * 32 + b] = r.x * inv;
        attnT[(size_t)(dbase + 1) * 32 + b] = r.y * inv;
        attnT[(size_t)(dbase + 2) * 32 + b] = r.z * inv;
        attnT[(size_t)(dbase + 3) * 32 + b] = r.w * inv;
    }
}

// ---------------------------------------------------------------------------
extern "C" void kernel_launch(void* const* d_in, const int* in_sizes, int n_in,
                              void* d_out, int out_size, void* d_ws, size_t ws_size,
                              hipStream_t stream) {
    const float* x       = (const float*)d_in[0];   // 32 x 4096
    const float* wqkv    = (const float*)d_in[1];   // 4096 x 6144
    const float* wo      = (const float*)d_in[2];   // 4096 x 4096
    const float* rot     = (const float*)d_in[3];   // 128 x 128
    float*       cache_k = (float*)d_in[4];         // 32 x 8 x 4096 x 128
    float*       cache_v = (float*)d_in[5];
    const int*   posp    = (const int*)d_in[6];
    float*       out     = (float*)d_out;           // 32 x 4096

    char* ws = (char*)d_ws;
    size_t off = 0;
    float* xT    = (float*)(ws + off); off += (size_t)DIM * 32 * 4;        // 512 KB
    float* xqkv  = (float*)(ws + off); off += (size_t)32 * QKVN * 4;       // 768 KB
    float* qr    = (float*)(ws + off); off += (size_t)32 * NH * HD * 4;    // 512 KB
    float* attnT = (float*)(ws + off); off += (size_t)NH * HD * 32 * 4;    // 512 KB
    float* partial = (float*)(ws + off);
    size_t avail = (ws_size > off) ? (ws_size - off) : 0;

    // split-K chunk counts bounded by workspace
    size_t slab1 = (size_t)32 * QKVN * 4;   // per-chunk partial for qkv gemm
    size_t slab4 = (size_t)32 * DIM * 4;    // per-chunk partial for out gemm
    int c1 = (int)(avail / slab1); if (c1 > 16) c1 = 16; if (c1 < 1) c1 = 1;
    int c4 = (int)(avail / slab4); if (c4 > 16) c4 = 16; if (c4 < 1) c4 = 1;
    int chunk1 = (DIM + c1 - 1) / c1;
    int chunk4 = (DIM + c4 - 1) / c4;

    // K0: transpose x
    k_transpose_x<<<DIM / 64, 256, 0, stream>>>(x, xT);
    // K1: xqkv partials + reduce
    k_gemm32_partial<<<(QKVN / 256) * c1, 256, 0, stream>>>(xT, wqkv, partial,
                                                            DIM, QKVN, chunk1);
    k_reduce_partial<<<(32 * QKVN) / 256, 256, 0, stream>>>(partial, xqkv, QKVN, c1);
    // K2: rope + cache scatter
    k_rope_scatter<<<BATCH * 48, 128, 0, stream>>>(xqkv, rot, qr, cache_k, cache_v, posp);
    // K3: attention
    k_attn_decode<<<BATCH * NKV, 256, 0, stream>>>(qr, cache_k, cache_v, posp, attnT);
    // K4: out partials + reduce
    k_gemm32_partial<<<(DIM / 256) * c4, 256, 0, stream>>>(attnT, wo, partial,
                                                           DIM, DIM, chunk4);
    k_reduce_partial<<<(32 * DIM) / 256, 256, 0, stream>>>(partial, out, DIM, c4);
}